// Round 6
// baseline (43.617 us; speedup 1.0000x reference)
//
#include <hip/hip_runtime.h>
#include <math.h>

#define NB 6   // GRID_N + K basis functions

typedef float f2 __attribute__((ext_vector_type(2)));

struct Params {
    float sb0[3], sp0[3];
    float b0;
    float sb1, sp1;
    float ki0, ki1;
};

__device__ __forceinline__ float fexp2(float x) { return __builtin_amdgcn_exp2f(x); }
__device__ __forceinline__ float flog2(float x) { return __builtin_amdgcn_logf(x); }
__device__ __forceinline__ float frcp(float x)  { return __builtin_amdgcn_rcpf(x); }
__device__ __forceinline__ float frsq(float x)  { return __builtin_amdgcn_rsqf(x); }

// Per-cell folded cubic (validated r5): S = a0+f(a1+f(a2+f a3)), S' = b0+f(b1+f b2).
__device__ __forceinline__ void spline_eval(float x, const float (*__restrict__ tab)[8],
                                            float& sp, float& dsp) {
    float u  = fmaf(x, 1.5f, 4.5f);
    float fi = floorf(u);
    float f  = u - fi;
    int   i  = (int)fi;
    float msk = (u >= 0.0f && u < 9.0f) ? 1.0f : 0.0f;
    i = i < 0 ? 0 : (i > 8 ? 8 : i);
    const float4 A  = *reinterpret_cast<const float4*>(&tab[i][0]);
    const float4 Bv = *reinterpret_cast<const float4*>(&tab[i][4]);
    sp  = msk * fmaf(fmaf(fmaf(A.w, f, A.z), f, A.y), f, A.x);
    dsp = msk * fmaf(fmaf(Bv.z, f, Bv.y), f, Bv.x);
}

__device__ __forceinline__ void silu_fd_v(f2 x, f2& s, f2& ds) {
    f2 t  = x * -1.44269504f;
    f2 e  = { fexp2(t.x), fexp2(t.y) };
    f2 oe = e + 1.0f;
    f2 sig = { frcp(oe.x), frcp(oe.y) };
    s = x * sig;
    f2 om = 1.0f - sig;
    ds = sig * (x * om + 1.0f);
}

// Two samples per call, all pure arithmetic in packed f32 pairs (v_pk_*).
// Math identical to r5's validated log2-space formulation.
__device__ void grad_pair(f2 s1, f2 s2, f2 s3, const Params& P,
                          const float (*__restrict__ tab)[9][8], f2 g[3]) {
    f2 a   = s1 * 2.0f + 1.0f;
    f2 d   = s2 * 2.0f + 1.0f;
    f2 b   = s3;
    f2 m   = (a + d) * 0.5f;
    f2 amd = a - d;
    f2 h2  = amd * amd * 0.25f + b * b;
    f2 irr;
    irr.x = h2.x > 0.0f ? frsq(h2.x) : 0.0f;   // JAX where: dr=0 at h2<=0
    irr.y = h2.y > 0.0f ? frsq(h2.y) : 0.0f;
    f2 r  = h2 * irr;                           // sqrt(h2), exactly 0 when masked
    f2 t1 = m - r, t2 = m + r;
    f2 det = t1 * t2;
    f2 invDet = { frcp(det.x), frcp(det.y) };
    f2 invt1 = t2 * invDet, invt2 = t1 * invDet;
    f2 Lt1 = { flog2(t1.x), flog2(t1.y) };
    f2 Lt2 = { flog2(t2.x), flog2(t2.y) };
    float k = P.ki0;
    f2 e0 = (Lt1 * (1.0f / 3.0f) - Lt2 * (1.0f / 6.0f)) * k;
    f2 e1 = (Lt2 * (1.0f / 3.0f) - Lt1 * (1.0f / 6.0f)) * k;
    f2 x0 = { fexp2(e0.x), fexp2(e0.y) };
    f2 x1 = { fexp2(e1.x), fexp2(e1.y) };
    f2 x2 = (Lt1 + Lt2) * (P.ki1 * 0.34657359f);

    // ---- layer 1 ----
    f2 xs[3] = { x0, x1, x2 };
    f2 hacc = { P.b0, P.b0 };
    f2 gx[3];
#pragma unroll
    for (int i = 0; i < 3; ++i) {
        float spa, dspa, spb, dspb;
        spline_eval(xs[i].x, tab[i], spa, dspa);
        spline_eval(xs[i].y, tab[i], spb, dspb);
        f2 sp  = { spa, spb };
        f2 dsp = { dspa, dspb };
        f2 si, dsi; silu_fd_v(xs[i], si, dsi);
        hacc = hacc + si * P.sb0[i] + sp * P.sp0[i];
        gx[i] = dsi * P.sb0[i] + dsp * P.sp0[i];
    }
    // ---- layer 2 ----
    float spa, dspa, spb, dspb;
    spline_eval(hacc.x, tab[3], spa, dspa);
    spline_eval(hacc.y, tab[3], spb, dspb);
    f2 sp2v  = { spa, spb };
    f2 dsp2v = { dspa, dspb };
    f2 si2, dsi2; silu_fd_v(hacc, si2, dsi2);
    f2 dWdh = dsi2 * P.sb1 + dsp2v * P.sp1;

    // ---- collapse to strain gradient ----
    f2 P0  = dWdh * gx[0] * x0 * k;
    f2 P1  = dWdh * gx[1] * x1 * k;
    f2 w2c = dWdh * gx[2];
    f2 A = P0 * invt1 * 0.5f;
    f2 B = P1 * invt2 * 0.5f;
    f2 C = invDet * (w2c * (0.5f * P.ki1) - (P0 + P1) * (1.0f / 6.0f));
    f2 dr0 = amd * irr * 0.25f;
    f2 dr2 = b * irr;
    f2 BmA = B - A;
    f2 h05 = (A + B) * 0.5f;
    f2 gA = h05 + BmA * dr0 + C * d;
    f2 gD = h05 - BmA * dr0 + C * a;
    f2 gB = BmA * dr2 - C * b * 2.0f;
    g[0] = gA * 2.0f;   // da/ds1 = 2
    g[1] = gD * 2.0f;   // dd/ds2 = 2
    g[2] = gB;          // db/ds3 = 1
}

__global__ __launch_bounds__(256) void kan_grad(
        const float* __restrict__ strain, float* __restrict__ out, int n,
        const float* __restrict__ c0, const float* __restrict__ sb0,
        const float* __restrict__ sp0, const float* __restrict__ b0,
        const float* __restrict__ c1, const float* __restrict__ sb1,
        const float* __restrict__ sp1, const float* __restrict__ ki0,
        const float* __restrict__ ki1) {
    __shared__ float tab[4][9][8];
    __shared__ float g0s[3];

    const int t = threadIdx.x;
    if (t < 36) {
        int tbl = t / 9, cell = t % 9;
        const float* cp = (tbl < 3) ? (c0 + tbl * NB) : c1;
        float cv[4];
#pragma unroll
        for (int kk = 0; kk < 4; ++kk) {
            int j = cell + kk - 3;
            cv[kk] = (j >= 0 && j < NB) ? cp[j] : 0.0f;
        }
        const float c16 = 1.0f / 6.0f;
        float a0 = (cv[0] + 4.0f * cv[1] + cv[2]) * c16;
        float a1 = (cv[2] - cv[0]) * 0.5f;
        float a2 = (cv[0] - 2.0f * cv[1] + cv[2]) * 0.5f;
        float a3 = (cv[3] - cv[0] + 3.0f * (cv[1] - cv[2])) * c16;
        tab[tbl][cell][0] = a0;
        tab[tbl][cell][1] = a1;
        tab[tbl][cell][2] = a2;
        tab[tbl][cell][3] = a3;
        tab[tbl][cell][4] = 1.5f * a1;
        tab[tbl][cell][5] = 3.0f * a2;
        tab[tbl][cell][6] = 4.5f * a3;
        tab[tbl][cell][7] = 0.0f;
    }

    Params P;
#pragma unroll
    for (int i = 0; i < 3; ++i) { P.sb0[i] = sb0[i]; P.sp0[i] = sp0[i]; }
    P.b0 = b0[0];
    P.sb1 = sb1[0]; P.sp1 = sp1[0];
    P.ki0 = ki0[0]; P.ki1 = ki1[0];

    __syncthreads();
    if (t == 0) {
        f2 z = { 0.0f, 0.0f };
        f2 g0v[3];
        grad_pair(z, z, z, P, tab, g0v);
        g0s[0] = g0v[0].x; g0s[1] = g0v[1].x; g0s[2] = g0v[2].x;
    }
    __syncthreads();
    const float g00 = g0s[0], g01 = g0s[1], g02 = g0s[2];

    const int ngroups = (n + 3) >> 2;  // 4 samples (= 3 float4 = 2 packed pairs)
    for (int gi = blockIdx.x * blockDim.x + threadIdx.x; gi < ngroups;
         gi += gridDim.x * blockDim.x) {
        int i0 = gi * 4;
        if (i0 + 4 <= n) {
            const float4* sp4 = reinterpret_cast<const float4*>(strain + (size_t)i0 * 3);
            float4 v0 = sp4[0], v1 = sp4[1], v2 = sp4[2];
            // pair0 = samples 0,1 ; pair1 = samples 2,3
            f2 p0s1 = { v0.x, v0.w }, p0s2 = { v0.y, v1.x }, p0s3 = { v0.z, v1.y };
            f2 p1s1 = { v1.z, v2.y }, p1s2 = { v1.w, v2.z }, p1s3 = { v2.x, v2.w };
            f2 g[3], gg[3];
            grad_pair(p0s1, p0s2, p0s3, P, tab, g);
            grad_pair(p1s1, p1s2, p1s3, P, tab, gg);
            float4* op4 = reinterpret_cast<float4*>(out + (size_t)i0 * 3);
            op4[0] = make_float4(g[0].x - g00, g[1].x - g01, g[2].x - g02,
                                 g[0].y - g00);
            op4[1] = make_float4(g[1].y - g01, g[2].y - g02,
                                 gg[0].x - g00, gg[1].x - g01);
            op4[2] = make_float4(gg[2].x - g02, gg[0].y - g00,
                                 gg[1].y - g01, gg[2].y - g02);
        } else {
            for (int i = i0; i < n; ++i) {
                f2 s1 = { strain[3 * i],     strain[3 * i]     };
                f2 s2 = { strain[3 * i + 1], strain[3 * i + 1] };
                f2 s3 = { strain[3 * i + 2], strain[3 * i + 2] };
                f2 g[3];
                grad_pair(s1, s2, s3, P, tab, g);
                out[3 * i]     = g[0].x - g00;
                out[3 * i + 1] = g[1].x - g01;
                out[3 * i + 2] = g[2].x - g02;
            }
        }
    }
}

extern "C" void kernel_launch(void* const* d_in, const int* in_sizes, int n_in,
                              void* d_out, int out_size, void* d_ws, size_t ws_size,
                              hipStream_t stream) {
    const float* strain = (const float*)d_in[0];
    const float* c0  = (const float*)d_in[1];
    const float* sb0 = (const float*)d_in[2];
    const float* sp0 = (const float*)d_in[3];
    const float* b0  = (const float*)d_in[4];
    const float* c1  = (const float*)d_in[5];
    const float* sb1 = (const float*)d_in[6];
    const float* sp1 = (const float*)d_in[7];
    // d_in[8] = b1: no effect on gradient
    const float* ki0 = (const float*)d_in[9];
    const float* ki1 = (const float*)d_in[10];

    int n = in_sizes[0] / 3;                 // number of samples
    int ngroups = (n + 3) / 4;
    int block = 256;
    int grid = (ngroups + block - 1) / block;
    if (grid > 8192) grid = 8192;

    kan_grad<<<grid, block, 0, stream>>>(strain, (float*)d_out, n,
                                         c0, sb0, sp0, b0, c1, sb1, sp1, ki0, ki1);
}

// Round 7
// 21.299 us; speedup vs baseline: 2.0479x; 2.0479x over previous
//
#include <hip/hip_runtime.h>
#include <math.h>

#define NB 6   // GRID_N + K basis functions

struct Params {
    float sb0[3], sp0[3];
    float b0;
    float sb1, sp1;
    float k3, k6, kh;   // ki0/3, ki0/6, ki0/2
    float cL;           // ki1 * 0.5 * ln2   (x2 = cL*(Lt1+Lt2))
    float ch;           // ki1 * 0.5
};

__device__ __forceinline__ float fexp2(float x) { return __builtin_amdgcn_exp2f(x); }
__device__ __forceinline__ float flog2(float x) { return __builtin_amdgcn_logf(x); }
__device__ __forceinline__ float frcp(float x)  { return __builtin_amdgcn_rcpf(x); }
__device__ __forceinline__ float frsq(float x)  { return __builtin_amdgcn_rsqf(x); }

// Per-cell folded cubic (validated r5), single 16B fetch:
//   S  = a0 + f(a1 + f(a2 + f a3))
//   S' = 1.5 * (a1 + f(2 a2 + 3 a3 f))
__device__ __forceinline__ void spline_eval(float x, const float4* __restrict__ tab,
                                            float& sp, float& dsp) {
    float u  = fmaf(x, 1.5f, 4.5f);
    float fi = floorf(u);
    float f  = u - fi;
    int   i  = (int)fi;
    bool  in = (u >= 0.0f && u < 9.0f);
    float msk  = in ? 1.0f : 0.0f;
    float msk15 = in ? 1.5f : 0.0f;
    i = i < 0 ? 0 : (i > 8 ? 8 : i);
    const float4 A = tab[i];
    sp  = msk  * fmaf(fmaf(fmaf(A.w, f, A.z), f, A.y), f, A.x);
    float a2z = A.z + A.z;
    float f3  = 3.0f * f;
    dsp = msk15 * fmaf(f, fmaf(f3, A.w, a2z), A.y);
}

__device__ __forceinline__ void silu_fd(float x, float& s, float& ds) {
    float e   = fexp2(-1.44269504f * x);
    float sig = frcp(1.0f + e);
    s  = x * sig;
    ds = sig * fmaf(x, 1.0f - sig, 1.0f);
}

// Analytic gradient, half-coordinate log2-space form (math identical to r5):
//   m = s1+s2+1 = (a+d)/2 ; q = s1-s2 = (a-d)/2 ; h2 = q^2 + b^2 ; r = sqrt(h2)
//   t1 = m-r, t2 = m+r ; det = t1 t2
//   x0 = exp2(k(Lt1/3 - Lt2/6)), x1 symm, x2 = ki1*0.5*ln(det)
//   g0 = 2(w+t), g1 = 2(w-t), g2 = b(u0-2C)
//   with A=kh P0' invt1, B=kh P1' invt2, u0=(B-A)irr, C=invDet(ch w2c - k6(P0'+P1')),
//        w = (A+B)/2 + C m, t = q(u0/2 - C).   dr=0 at h2<=0 (JAX where).
__device__ void grad_sample(float s1, float s2, float s3, const Params& P,
                            const float4 (*__restrict__ tab)[9], float g[3]) {
    float q   = s1 - s2;
    float m   = s1 + s2 + 1.0f;
    float b   = s3;
    float h2  = fmaf(q, q, b * b);
    float irr = h2 > 0.0f ? frsq(h2) : 0.0f;   // 1/r (0 at h2<=0)
    float r   = h2 * irr;                       // sqrt(h2), exactly 0 when masked
    float t1  = m - r, t2 = m + r;
    float invDet = frcp(t1 * t2);
    float invt1 = t2 * invDet, invt2 = t1 * invDet;
    float Lt1 = flog2(t1), Lt2 = flog2(t2);
    float x0  = fexp2(fmaf(Lt1, P.k3, -Lt2 * P.k6));
    float x1  = fexp2(fmaf(Lt2, P.k3, -Lt1 * P.k6));
    float x2  = (Lt1 + Lt2) * P.cL;

    // ---- layer 1 ----
    float xs[3] = {x0, x1, x2};
    float hacc  = P.b0;
    float gx[3];
#pragma unroll
    for (int i = 0; i < 3; ++i) {
        float sp, dsp;
        spline_eval(xs[i], tab[i], sp, dsp);
        float si, dsi; silu_fd(xs[i], si, dsi);
        hacc += P.sb0[i] * si + P.sp0[i] * sp;
        gx[i] = P.sb0[i] * dsi + P.sp0[i] * dsp;
    }
    // ---- layer 2 ----
    float sp2, dsp2;
    spline_eval(hacc, tab[3], sp2, dsp2);
    float si2, dsi2; silu_fd(hacc, si2, dsi2);
    float dWdh = P.sb1 * dsi2 + P.sp1 * dsp2;

    // ---- collapse ----
    float P0 = dWdh * gx[0] * x0;
    float P1 = dWdh * gx[1] * x1;
    float w2c = dWdh * gx[2];
    float A = P.kh * P0 * invt1;
    float B = P.kh * P1 * invt2;
    float C = invDet * fmaf(-P.k6, P0 + P1, P.ch * w2c);
    float u0 = (B - A) * irr;
    float w  = fmaf(C, m, 0.5f * (A + B));
    float t  = q * fmaf(0.5f, u0, -C);
    g[0] = 2.0f * (w + t);
    g[1] = 2.0f * (w - t);
    g[2] = b * fmaf(-2.0f, C, u0);
}

__global__ __launch_bounds__(256) void kan_grad(
        const float* __restrict__ strain, float* __restrict__ out, int n,
        const float* __restrict__ c0, const float* __restrict__ sb0,
        const float* __restrict__ sp0, const float* __restrict__ b0,
        const float* __restrict__ c1, const float* __restrict__ sb1,
        const float* __restrict__ sp1, const float* __restrict__ ki0,
        const float* __restrict__ ki1) {
    __shared__ float4 tab[4][9];
    __shared__ float g0s[3];

    const int t = threadIdx.x;
    if (t < 36) {
        int tbl = t / 9, cell = t % 9;
        const float* cp = (tbl < 3) ? (c0 + tbl * NB) : c1;
        float cv[4];
#pragma unroll
        for (int kk = 0; kk < 4; ++kk) {
            int j = cell + kk - 3;
            cv[kk] = (j >= 0 && j < NB) ? cp[j] : 0.0f;
        }
        const float c16 = 1.0f / 6.0f;
        float a0 = (cv[0] + 4.0f * cv[1] + cv[2]) * c16;
        float a1 = (cv[2] - cv[0]) * 0.5f;
        float a2 = (cv[0] - 2.0f * cv[1] + cv[2]) * 0.5f;
        float a3 = (cv[3] - cv[0] + 3.0f * (cv[1] - cv[2])) * c16;
        tab[tbl][cell] = make_float4(a0, a1, a2, a3);
    }

    Params P;
#pragma unroll
    for (int i = 0; i < 3; ++i) { P.sb0[i] = sb0[i]; P.sp0[i] = sp0[i]; }
    P.b0 = b0[0];
    P.sb1 = sb1[0]; P.sp1 = sp1[0];
    float k = ki0[0], l = ki1[0];
    P.k3 = k * (1.0f / 3.0f);
    P.k6 = k * (1.0f / 6.0f);
    P.kh = k * 0.5f;
    P.cL = l * 0.34657359f;
    P.ch = l * 0.5f;

    __syncthreads();
    if (t == 0) {
        float g0[3];
        grad_sample(0.0f, 0.0f, 0.0f, P, tab, g0);
        g0s[0] = g0[0]; g0s[1] = g0[1]; g0s[2] = g0[2];
    }
    __syncthreads();
    const float g00 = g0s[0], g01 = g0s[1], g02 = g0s[2];

    const int ngroups = (n + 7) >> 3;  // 8 samples (= 6 float4) per thread-task
    for (int gi = blockIdx.x * blockDim.x + threadIdx.x; gi < ngroups;
         gi += gridDim.x * blockDim.x) {
        int i0 = gi * 8;
        if (i0 + 8 <= n) {
            const float4* sp4 = reinterpret_cast<const float4*>(strain + (size_t)i0 * 3);
            float4 v[6];
#pragma unroll
            for (int kk = 0; kk < 6; ++kk) v[kk] = sp4[kk];
            const float* in = reinterpret_cast<const float*>(v);
            float o[24];
#pragma unroll
            for (int kk = 0; kk < 8; ++kk) {
                float g[3];
                grad_sample(in[3 * kk], in[3 * kk + 1], in[3 * kk + 2], P, tab, g);
                o[3 * kk]     = g[0] - g00;
                o[3 * kk + 1] = g[1] - g01;
                o[3 * kk + 2] = g[2] - g02;
            }
            float4* op4 = reinterpret_cast<float4*>(out + (size_t)i0 * 3);
            const float4* ov = reinterpret_cast<const float4*>(o);
#pragma unroll
            for (int kk = 0; kk < 6; ++kk) op4[kk] = ov[kk];
        } else {
            for (int i = i0; i < n; ++i) {
                float g[3];
                grad_sample(strain[3 * i], strain[3 * i + 1], strain[3 * i + 2], P,
                            tab, g);
                out[3 * i]     = g[0] - g00;
                out[3 * i + 1] = g[1] - g01;
                out[3 * i + 2] = g[2] - g02;
            }
        }
    }
}

extern "C" void kernel_launch(void* const* d_in, const int* in_sizes, int n_in,
                              void* d_out, int out_size, void* d_ws, size_t ws_size,
                              hipStream_t stream) {
    const float* strain = (const float*)d_in[0];
    const float* c0  = (const float*)d_in[1];
    const float* sb0 = (const float*)d_in[2];
    const float* sp0 = (const float*)d_in[3];
    const float* b0  = (const float*)d_in[4];
    const float* c1  = (const float*)d_in[5];
    const float* sb1 = (const float*)d_in[6];
    const float* sp1 = (const float*)d_in[7];
    // d_in[8] = b1: no effect on gradient
    const float* ki0 = (const float*)d_in[9];
    const float* ki1 = (const float*)d_in[10];

    int n = in_sizes[0] / 3;                 // number of samples
    int ngroups = (n + 7) / 8;
    int block = 256;
    int grid = (ngroups + block - 1) / block;
    if (grid > 8192) grid = 8192;

    kan_grad<<<grid, block, 0, stream>>>(strain, (float*)d_out, n,
                                         c0, sb0, sp0, b0, c1, sb1, sp1, ki0, ki1);
}